// Round 7
// baseline (1179.333 us; speedup 1.0000x reference)
//
#include <hip/hip_runtime.h>
#include <hip/hip_bf16.h>

#define NT 1024
#define NNODES 4096
#define ECAP 65536   // max arcs after iteration-1 symmetrization (E0 <= 32768)

// ---------------- block-wide exclusive scan over NT=1024 values ----------------
__device__ __forceinline__ int blockScanExcl(int v, int* s_w, int* total) {
    const int tid  = threadIdx.x;
    const int lane = tid & 63;
    const int wv   = tid >> 6;
    int x = v;
#pragma unroll
    for (int off = 1; off < 64; off <<= 1) {
        int t = __shfl_up(x, off, 64);
        if (lane >= off) x += t;
    }
    if (lane == 63) s_w[wv] = x;
    __syncthreads();
    if (tid < 16) {
        int y = s_w[tid];
#pragma unroll
        for (int off = 1; off < 16; off <<= 1) {
            int t = __shfl_up(y, off, 16);
            if (tid >= off) y += t;
        }
        s_w[tid] = y;
    }
    __syncthreads();
    int base = wv ? s_w[wv - 1] : 0;
    int tot  = s_w[15];
    __syncthreads();   // protect s_w reuse
    *total = tot;
    return base + x - v;   // exclusive prefix
}

// ================= Phase A1, grid=2 =================
// block 0: preamble (no sort): copy+hist, hub0, iter0, append, CSR, dumps
// block 1: stable counting sort by degree desc -> ORDG (single-wave match-any)
__global__ __launch_bounds__(NT, 1)
void phaseA1(const int* __restrict__ ei, int E0,
             int* __restrict__ U, int* __restrict__ V,
             unsigned int* __restrict__ BM,
             int* __restrict__ NBR, int* __restrict__ OTH,
             int* __restrict__ ORDG, int* __restrict__ ROFFG, int* __restrict__ RENDG,
             int* __restrict__ STAMPG, int* __restrict__ HAND)
{
    // ---- block 1 arrays ----
    __shared__ int t_deg[NNODES];
    __shared__ int t_cur[NNODES];
    __shared__ int t_bc[4];
    // ---- block 0 arrays ----
    __shared__ unsigned char  s_vis[NNODES];
    __shared__ unsigned int   s_hb[NNODES / 32];
    __shared__ int s_roff[NNODES];
    __shared__ int s_rend[NNODES];
    __shared__ int s_tmp[NNODES];
    __shared__ int s_w[16];
    __shared__ int s_bc[16];

    const int tid = threadIdx.x;

    if (blockIdx.x == 1) {
        // ================= stable argsort by degree desc =================
        for (int i = tid; i < NNODES; i += NT) { t_deg[i] = 0; t_cur[i] = 0; }
        if (tid < 4) t_bc[tid] = 0;
        __syncthreads();
        for (int i = tid; i < E0; i += NT)
            if (ei[2 * i + 1] != 0) t_bc[1] = 1;
        __syncthreads();
        const int is64b = !t_bc[1];
        for (int e = tid; e < E0; e += NT) {
            int uu = ei[is64b ? 2 * e : e];
            int vv = ei[is64b ? 2 * (E0 + e) : (E0 + e)];
            atomicAdd(&t_deg[uu], 1);
            atomicAdd(&t_deg[vv], 1);
        }
        __syncthreads();
        for (int n = tid; n < NNODES; n += NT) atomicMax(&t_bc[2], t_deg[n]);
        __syncthreads();
        const int maxd = t_bc[2];
        for (int n = tid; n < NNODES; n += NT) atomicAdd(&t_cur[t_deg[n]], 1);
        __syncthreads();
        if (tid < 64) {        // single wave: cursor + stable placement
            const int ln = tid;
            const unsigned long long ltm = (1ull << ln) - 1ull;
            // cursor[d] = count(deg > d) = NNODES - inclusive_prefix(hist)[d]
            int carry = 0;
            for (int b0 = 0; b0 <= maxd; b0 += 64) {
                int d = b0 + ln;
                int v = (d <= maxd) ? t_cur[d] : 0;
                int x = v;
#pragma unroll
                for (int off = 1; off < 64; off <<= 1) {
                    int t = __shfl_up(x, off, 64);
                    if (ln >= off) x += t;
                }
                if (d <= maxd) t_cur[d] = NNODES - (carry + x);
                carry += __shfl(x, 63, 64);
            }
            // placement: groups in index order, match-any via bit ballots
            const int nb = 32 - __clz(maxd | 1);
            for (int g = 0; g < NNODES / 64; ++g) {
                int n = g * 64 + ln;
                int d = t_deg[n];
                unsigned long long m = ~0ull;
                for (int b = 0; b < nb; ++b) {
                    unsigned long long bb = __ballot((d >> b) & 1);
                    m &= ((d >> b) & 1) ? bb : ~bb;
                }
                int rank   = __popcll(m & ltm);
                int leader = __ffsll((long long)m) - 1;
                int base = 0;
                if (ln == leader) { base = t_cur[d]; t_cur[d] = base + __popcll(m); }
                base = __shfl(base, leader, 64);
                ORDG[base + rank] = n;
            }
        }
        return;
    }

    // ================= block 0: preamble =================
    for (int i = tid; i < NNODES; i += NT) { s_vis[i] = 0; s_tmp[i] = 0; }
    for (int i = tid; i < NNODES / 32; i += NT) s_hb[i] = 0;
    if (tid < 16) s_bc[tid] = 0;
    if (tid == 0) s_bc[0] = 0x7fffffff;
    __syncthreads();

    // ---- detect int64 vs int32 edge buffer ----
    for (int i = tid; i < E0; i += NT)
        if (ei[2 * i + 1] != 0) s_bc[9] = 1;
    __syncthreads();
    const int is64 = !s_bc[9];

    // ---- copy edges + degree histogram (I+O) ----
    for (int e = tid; e < E0; e += NT) {
        int uu = ei[is64 ? 2 * e : e];
        int vv = ei[is64 ? 2 * (E0 + e) : (E0 + e)];
        U[e] = uu; V[e] = vv;
        atomicAdd(&s_tmp[uu], 1);
        atomicAdd(&s_tmp[vv], 1);
    }
    __syncthreads();
    for (int n = tid; n < NNODES; n += NT) atomicMax(&s_bc[7], s_tmp[n]);
    __syncthreads();
    const int maxd = s_bc[7];
    // hub0 = min index among max-degree nodes (stable argsort head)
    for (int n = tid; n < NNODES; n += NT)
        if (s_tmp[n] == maxd) atomicMin(&s_bc[0], n);
    __syncthreads();

    // ---- iteration 0 (full-array scans, eager relabel) ----
    if (tid == 0) { s_vis[s_bc[0]] = 1; }
    __syncthreads();
    {
        const int node = s_bc[0];
        for (int e = tid; e < E0; e += NT) {
            int uu = U[e], vv = V[e];
            if (uu == node) {
                int w = vv; unsigned m = 1u << (w & 31);
                unsigned old = atomicOr(&s_hb[w >> 5], m);
                if (!(old & m)) { int i = atomicAdd(&s_bc[2], 1); s_tmp[i] = w; s_vis[w] = 1; }
            }
            if (vv == node) {
                int w = uu; unsigned m = 1u << (w & 31);
                unsigned old = atomicOr(&s_hb[w >> 5], m);
                if (!(old & m)) { int i = atomicAdd(&s_bc[2], 1); s_tmp[i] = w; s_vis[w] = 1; }
            }
        }
        __syncthreads();
        // eager relabel Hn = H \ {node} (U/V frozen afterwards)
        for (int e = tid; e < E0; e += NT) {
            int uu = U[e];
            if (uu != node && ((s_hb[uu >> 5] >> (uu & 31)) & 1)) U[e] = node;
            int vv = V[e];
            if (vv != node && ((s_hb[vv >> 5] >> (vv & 31)) & 1)) V[e] = node;
        }
        __syncthreads();
    }

    // ---- symmetry append: bitmap + chunked single-scan compaction ----
    {
        uint4* bm4 = (uint4*)BM;
        for (int i = tid; i < (1 << 17); i += NT) bm4[i] = make_uint4(0, 0, 0, 0);
    }
    __syncthreads();
    for (int e = tid; e < E0; e += NT) {
        int uu = U[e], vv = V[e];
        if (uu != vv) {
            unsigned code = ((unsigned)uu << 12) | (unsigned)vv;
            atomicOr(&BM[code >> 5], 1u << (code & 31));
        }
    }
    __syncthreads();
    int E1;
    {
        const int chA = (E0 + NT - 1) / NT;   // <= 64
        const int begA = tid * chA;
        unsigned long long mA = 0ull;
        for (int j = 0; j < chA; ++j) {
            int e = begA + j;
            if (e < E0) {
                int uu = U[e], vv = V[e];
                if (uu != vv) {
                    unsigned rc = ((unsigned)vv << 12) | (unsigned)uu;
                    unsigned old = atomicOr(&BM[rc >> 5], 0u);   // L2 read
                    if (!((old >> (rc & 31)) & 1u)) mA |= 1ull << j;
                }
            }
        }
        int tot;
        int off = blockScanExcl(__popcll(mA), s_w, &tot);
        int r = off;
        for (int j = 0; j < chA; ++j) if ((mA >> j) & 1) {
            int e = begA + j;
            U[E0 + r] = V[e]; V[E0 + r] = U[e];
            r++;
        }
        E1 = E0 + tot;
    }
    __syncthreads();

    // ---- build static CSR (other-endpoint only; BM region reused as OTH/NBR) ----
    for (int n = tid; n < NNODES; n += NT) s_roff[n] = 0;
    __syncthreads();
    for (int e = tid; e < E1; e += NT) {
        int uu = U[e], vv = V[e];
        if (uu != vv) { atomicAdd(&s_roff[uu], 1); atomicAdd(&s_roff[vv], 1); }
    }
    __syncthreads();
    {
        int n0 = tid * 4;
        int c0 = s_roff[n0], c1 = s_roff[n0 + 1], c2 = s_roff[n0 + 2], c3 = s_roff[n0 + 3];
        int tot;
        int off = blockScanExcl(c0 + c1 + c2 + c3, s_w, &tot);
        int st = off;
        s_roff[n0] = st;     s_rend[n0] = st;     st += c0;
        s_roff[n0 + 1] = st; s_rend[n0 + 1] = st; st += c1;
        s_roff[n0 + 2] = st; s_rend[n0 + 2] = st; st += c2;
        s_roff[n0 + 3] = st; s_rend[n0 + 3] = st;
    }
    __syncthreads();
    for (int e = tid; e < E1; e += NT) {
        int uu = U[e], vv = V[e];
        if (uu != vv) {
            int p = atomicAdd(&s_rend[uu], 1);
            int q = atomicAdd(&s_rend[vv], 1);
            OTH[p] = vv; OTH[q] = uu;
        }
    }
    __syncthreads();
    {   // flush iter-0 staged H into global NBR
        const int cnt0 = s_bc[2];
        for (int i = tid; i < cnt0; i += NT) NBR[i] = s_tmp[i];
    }
    // ---- dumps ----
    for (int i = tid; i < NNODES; i += NT) {
        ROFFG[i]  = s_roff[i];
        RENDG[i]  = s_rend[i];
        STAMPG[i] = s_vis[i] ? 0 : -1;   // visited <=> stamp >= 0
    }
    if (tid == 0) { HAND[0] = E1; HAND[1] = s_bc[2]; HAND[2] = s_bc[0]; }
}

// ================= Phase A2: main loop, single wave, speculative prefetch =================
__global__ __launch_bounds__(64, 1)
void phaseA2(const int* __restrict__ OTH, int* __restrict__ NBR,
             const int* __restrict__ ORDG, const int* __restrict__ ROFFG,
             const int* __restrict__ RENDG, const int* __restrict__ STAMPG,
             const int* __restrict__ HAND,
             int* __restrict__ SEL, int* __restrict__ CNTS,
             int* __restrict__ NST, int* __restrict__ FIL, int* __restrict__ SC,
             int* __restrict__ LABG, int* __restrict__ RNKG)
{
    __shared__ unsigned short s_ord[NNODES];
    __shared__ int s_stamp[NNODES];               // -1 unvisited; >=0 visited; reused as rank
    __shared__ unsigned short s_lab[NNODES];      // lazy label (chain <= 1)
    __shared__ unsigned char  s_sel[NNODES];
    __shared__ int s_cnt[NNODES];
    __shared__ unsigned short s_so[NNODES];
    __shared__ int s_roff[NNODES];
    __shared__ int s_rend[NNODES];

    const int ln = threadIdx.x;
    const unsigned long long ltm = (1ull << ln) - 1ull;

    for (int i = ln; i < NNODES; i += 64) {
        s_ord[i]   = (unsigned short)ORDG[i];
        s_stamp[i] = STAMPG[i];
        s_lab[i]   = (unsigned short)i;
        s_sel[i]   = 0; s_cnt[i] = 0;
        s_roff[i]  = ROFFG[i];
        s_rend[i]  = RENDG[i];
    }
    int cursor = HAND[1];              // wave-uniform NBR cursor (no atomics)
    const int hub0 = HAND[2];
    if (ln == 0) { s_sel[hub0] = 1; s_so[0] = (unsigned short)hub0; s_cnt[0] = cursor; }

    auto wsel = [&](int& pp) -> int {  // first order-entry with stamp<0 at pos>=pp
        while (pp < NNODES) {
            int idx = pp + ln;
            int nd  = (idx < NNODES) ? (int)s_ord[idx] : 0;
            int st  = (idx < NNODES) ? s_stamp[nd] : 0;
            unsigned long long bal = __ballot(st < 0);
            if (bal) {
                int sl = __ffsll((long long)bal) - 1;
                pp += sl + 1;
                return __shfl(nd, sl, 64);
            }
            pp += 64;
        }
        return -1;
    };

    int p = 0, k = 1;
    int node = wsel(p);
    int rb = 0, re = 0, oA = -1, oB = -1;
    if (node >= 0) {
        rb = s_roff[node]; re = s_rend[node];
        oA = (rb + ln < re) ? OTH[rb + ln] : -1;
        oB = (rb + 64 + ln < re) ? OTH[rb + 64 + ln] : -1;
    }
    while (node >= 0) {
        if (ln == 0) { atomicExch(&s_stamp[node], k); s_sel[node] = 1; s_so[k] = (unsigned short)node; }
        // speculative next hub (stamps read pre-row: wave LDS is in-order)
        int pc = p;
        int cand = wsel(pc);
        int rb2 = 0, re2 = 0, oA2 = -1, oB2 = -1;
        if (cand >= 0) {
            rb2 = s_roff[cand]; re2 = s_rend[cand];
            oA2 = (rb2 + ln < re2) ? OTH[rb2 + ln] : -1;
            oB2 = (rb2 + 64 + ln < re2) ? OTH[rb2 + 64 + ln] : -1;
        }
        // ---- process row of `node` ----
        int total = 0; bool candhit = false;
        auto proc = [&](int o) {
            bool isnew = false; int w = -1;
            if (o >= 0) {
                w = (int)s_lab[o];
                int sv  = s_sel[w];
                int old = atomicMax(&s_stamp[w], k);   // dedup + visited mark in one op
                if (old < k) {                          // node itself has stamp==k: auto-skip
                    isnew = true;
                    if (!sv) s_lab[w] = (unsigned short)node;   // absorb (chain <= 1)
                    if (w == cand) candhit = true;
                }
            }
            unsigned long long b = __ballot(isnew);
            if (isnew) NBR[cursor + __popcll(b & ltm)] = w;
            int cc = __popcll(b);
            cursor += cc; total += cc;
        };
        proc(oA); proc(oB);
        for (int s0 = rb + 128; s0 < re; s0 += 64) {   // rare long rows
            int s = s0 + ln;
            proc((s < re) ? OTH[s] : -1);
        }
        if (ln == 0) s_cnt[k] = total;
        if (__ballot(candhit)) {        // mis-speculation (~rare): reselect + reload
            cand = wsel(pc);
            if (cand >= 0) {
                rb2 = s_roff[cand]; re2 = s_rend[cand];
                oA2 = (rb2 + ln < re2) ? OTH[rb2 + ln] : -1;
                oB2 = (rb2 + 64 + ln < re2) ? OTH[rb2 + 64 + ln] : -1;
            }
        }
        p = pc; node = cand; rb = rb2; re = re2; oA = oA2; oB = oB2;
        k++;
    }
    const int K = k;

    // ---- rank of selected nodes among sorted(select); into s_stamp ----
    {
        int base = 0;
        for (int c = 0; c < NNODES / 64; ++c) {
            int n = c * 64 + ln;
            int f = s_sel[n];
            unsigned long long b = __ballot(f);
            s_stamp[n] = base + __popcll(b & ltm);
            base += __popcll(b);
        }
    }
    // ---- SEL / CNTS / NST ----
    {
        int nb = 0;
        for (int c = 0; c * 64 < K; ++c) {
            int i = c * 64 + ln;
            int cv = (i < K) ? s_cnt[i] : 0;
            int x = cv;
#pragma unroll
            for (int off = 1; off < 64; off <<= 1) {
                int t = __shfl_up(x, off, 64);
                if (ln >= off) x += t;
            }
            if (i < K) { NST[i] = nb + x - cv; CNTS[i] = cv; SEL[i] = (int)s_so[i]; }
            nb += __shfl(x, 63, 64);
        }
    }
    // ---- FIL forward-fill via ballot + clz ----
    {
        int carry = 0;
        for (int c = 0; c * 64 < K; ++c) {
            int i = c * 64 + ln;
            int f = (i < K) && (s_cnt[i] > 0);
            unsigned long long b = __ballot(f);
            unsigned long long m = b & ((ln == 63) ? ~0ull : ((1ull << (ln + 1)) - 1ull));
            int fil = m ? (c * 64 + 63 - __clzll(m)) : carry;
            if (i < K) FIL[i] = fil;
            carry = b ? (c * 64 + 63 - __clzll(b)) : carry;
        }
    }
    if (ln == 0) SC[0] = K;
    for (int i = ln; i < NNODES; i += 64) {
        LABG[i] = (int)s_lab[i];
        RNKG[i] = s_stamp[i];
    }
}

// ================= Phase A3: final compaction, chunked single-scan =================
__global__ __launch_bounds__(NT, 1)
void phaseA3(const int* __restrict__ U, const int* __restrict__ V,
             const int* __restrict__ LABG, const int* __restrict__ RNKG,
             const int* __restrict__ HAND, int* __restrict__ SC,
             float* __restrict__ out)
{
    __shared__ unsigned short l_lab[NNODES];
    __shared__ int l_rnk[NNODES];
    __shared__ int s_w[16];

    const int tid = threadIdx.x;
    for (int i = tid; i < NNODES; i += NT) {
        l_lab[i] = (unsigned short)LABG[i];
        l_rnk[i] = RNKG[i];
    }
    __syncthreads();

    const int E1 = HAND[0];
    const int K  = SC[0];
    const int ch = (E1 + NT - 1) / NT;    // <= 64
    const int beg = tid * ch;
    unsigned long long mF = 0ull;
    for (int j = 0; j < ch; ++j) {
        int e = beg + j;
        if (e < E1) {
            int uu = (int)l_lab[U[e]], vv = (int)l_lab[V[e]];
            if (uu != vv) mF |= 1ull << j;
        }
    }
    int Ef;
    int off = blockScanExcl(__popcll(mF), s_w, &Ef);
    const size_t obase = (size_t)K * 8192;
    int r = off;
    for (int j = 0; j < ch; ++j) if ((mF >> j) & 1) {
        int e = beg + j;
        out[obase + (size_t)r]              = (float)l_rnk[(int)l_lab[U[e]]];
        out[obase + (size_t)Ef + (size_t)r] = (float)l_rnk[(int)l_lab[V[e]]];
        r++;
    }
    if (tid == 0) SC[1] = Ef;
}

// ---------------- Phase B: END rows, 4-way column split for balance ----------------
__global__ __launch_bounds__(256, 4)
void phaseB(const float* __restrict__ x,
            const float* __restrict__ W1, const float* __restrict__ W2,
            const float* __restrict__ B1, const float* __restrict__ B2,
            const int* __restrict__ NBR, const int* __restrict__ SEL,
            const int* __restrict__ CNTS, const int* __restrict__ NST,
            const int* __restrict__ FIL, const int* __restrict__ SC,
            float* __restrict__ out)
{
    const int K = SC[0];
    const int k = blockIdx.x;
    if (k >= K) return;
    const int kk   = FIL[k];
    const int node = SEL[kk];
    const int cnt  = CNTS[kk];
    const int st   = NST[kk];
    const int c    = blockIdx.y * 256 + threadIdx.x;   // float4 column in [0,1024)
    const float4* x4 = (const float4*)x;

    float4 acc = make_float4(0.f, 0.f, 0.f, 0.f);
    for (int r = 0; r < cnt; ++r) {
        const float4* row = x4 + (size_t)NBR[st + r] * 1024;
        float4 t = row[c];
        acc.x += t.x; acc.y += t.y; acc.z += t.z; acc.w += t.w;
    }

    const float fc  = (float)cnt;
    const float inv = 1.0f / (float)(cnt > 1 ? cnt : 1);
    float4 w1 = ((const float4*)W1)[c], b1 = ((const float4*)B1)[c];
    float4 w2 = ((const float4*)W2)[c], b2 = ((const float4*)B2)[c];
    float4 xv = (x4 + (size_t)node * 1024)[c];
    float4 pd, pm;
    pd.x = xv.x * w2.x + b2.x;
    pd.y = xv.y * w2.y + b2.y;
    pd.z = xv.z * w2.z + b2.z;
    pd.w = xv.w * w2.w + b2.w;
    pm.x = (acc.x * w1.x + fc * b1.x) * inv;
    pm.y = (acc.y * w1.y + fc * b1.y) * inv;
    pm.z = (acc.z * w1.z + fc * b1.z) * inv;
    pm.w = (acc.w * w1.w + fc * b1.w) * inv;
    float4* o4 = (float4*)(out + (size_t)k * 8192);
    o4[c] = pd;
    o4[1024 + c] = pm;
}

extern "C" void kernel_launch(void* const* d_in, const int* in_sizes, int n_in,
                              void* d_out, int out_size, void* d_ws, size_t ws_size,
                              hipStream_t stream)
{
    const float* x  = (const float*)d_in[0];
    const int*   ei = (const int*)d_in[1];
    const float* W1 = (const float*)d_in[2];
    const float* W2 = (const float*)d_in[3];
    const float* B1 = (const float*)d_in[4];
    const float* B2 = (const float*)d_in[5];
    const int E0 = in_sizes[1] / 2;

    char* w = (char*)d_ws;
    int* U = (int*)w;                         // [ECAP]
    int* V = U + ECAP;                        // [ECAP]
    unsigned int* BM = (unsigned int*)(V + ECAP);   // 2 MB bitmap (iter-0 only)
    int* OTH = (int*)BM;                      // [2*ECAP] static CSR other-endpoint
    int* NBR = OTH + 2 * ECAP;                // [2*ECAP]
    char* meta = (char*)BM + (2u << 20);
    int* SEL    = (int*)meta;
    int* CNTS   = SEL    + NNODES;
    int* NST    = CNTS   + NNODES;
    int* FIL    = NST    + NNODES;
    int* SC     = FIL    + NNODES;            // [16]
    int* ORDG   = SC     + 16;
    int* ROFFG  = ORDG   + NNODES;
    int* RENDG  = ROFFG  + NNODES;
    int* LABG   = RENDG  + NNODES;
    int* RNKG   = LABG   + NNODES;
    int* STAMPG = RNKG   + NNODES;
    int* HAND   = STAMPG + NNODES;            // [16]
    float* out = (float*)d_out;

    hipLaunchKernelGGL(phaseA1, dim3(2), dim3(NT), 0, stream,
                       ei, E0, U, V, BM, NBR, OTH, ORDG, ROFFG, RENDG, STAMPG, HAND);
    hipLaunchKernelGGL(phaseA2, dim3(1), dim3(64), 0, stream,
                       OTH, NBR, ORDG, ROFFG, RENDG, STAMPG, HAND,
                       SEL, CNTS, NST, FIL, SC, LABG, RNKG);
    hipLaunchKernelGGL(phaseA3, dim3(1), dim3(NT), 0, stream,
                       U, V, LABG, RNKG, HAND, SC, out);
    hipLaunchKernelGGL(phaseB, dim3(NNODES, 4), dim3(256), 0, stream,
                       x, W1, W2, B1, B2, NBR, SEL, CNTS, NST, FIL, SC, out);
}

// Round 8
// 977.498 us; speedup vs baseline: 1.2065x; 1.2065x over previous
//
#include <hip/hip_runtime.h>
#include <hip/hip_bf16.h>

#define NT 1024
#define NNODES 4096
#define ECAP 65536   // max arcs after iteration-1 symmetrization (E0 <= 32768)

// ---------------- block-wide exclusive scan over NT=1024 values ----------------
__device__ __forceinline__ int blockScanExcl(int v, int* s_w, int* total) {
    const int tid  = threadIdx.x;
    const int lane = tid & 63;
    const int wv   = tid >> 6;
    int x = v;
#pragma unroll
    for (int off = 1; off < 64; off <<= 1) {
        int t = __shfl_up(x, off, 64);
        if (lane >= off) x += t;
    }
    if (lane == 63) s_w[wv] = x;
    __syncthreads();
    if (tid < 16) {
        int y = s_w[tid];
#pragma unroll
        for (int off = 1; off < 16; off <<= 1) {
            int t = __shfl_up(y, off, 16);
            if (tid >= off) y += t;
        }
        s_w[tid] = y;
    }
    __syncthreads();
    int base = wv ? s_w[wv - 1] : 0;
    int tot  = s_w[15];
    __syncthreads();   // protect s_w reuse
    *total = tot;
    return base + x - v;   // exclusive prefix
}

// ================= Phase A1: preamble (R4-exact), dump handoff state =================
// s_bc slots: 0=node 2=nbrCnt 4=orderBase 5=appendBase 7=maxdeg 9=not64
__global__ __launch_bounds__(NT, 1)
void phaseA1(const int* __restrict__ ei, int E0,
             int* __restrict__ U, int* __restrict__ V,
             unsigned int* __restrict__ BM,
             int* __restrict__ NBR, int* __restrict__ OTH,
             int* __restrict__ ORDV, int* __restrict__ ROFFG, int* __restrict__ RENDG,
             int* __restrict__ HAND)
{
    __shared__ unsigned short s_order[NNODES];
    __shared__ unsigned char  s_vis[NNODES];
    __shared__ unsigned int   s_hb[NNODES / 32];
    __shared__ int s_roff[NNODES];
    __shared__ int s_rend[NNODES];
    __shared__ int s_tmp[NNODES];
    __shared__ int s_w[16];
    __shared__ int s_bc[16];

    const int tid = threadIdx.x;

    for (int i = tid; i < NNODES; i += NT) { s_vis[i] = 0; s_tmp[i] = 0; }
    for (int i = tid; i < NNODES / 32; i += NT) s_hb[i] = 0;
    if (tid < 16) s_bc[tid] = 0;
    __syncthreads();

    // ---- detect int64 vs int32 edge buffer ----
    for (int i = tid; i < E0; i += NT)
        if (ei[2 * i + 1] != 0) s_bc[9] = 1;
    __syncthreads();
    const int is64 = !s_bc[9];

    // ---- copy edges + degree histogram (I+O) ----
    for (int e = tid; e < E0; e += NT) {
        int uu = ei[is64 ? 2 * e : e];
        int vv = ei[is64 ? 2 * (E0 + e) : (E0 + e)];
        U[e] = uu; V[e] = vv;
        atomicAdd(&s_tmp[uu], 1);
        atomicAdd(&s_tmp[vv], 1);
    }
    __syncthreads();
    for (int n = tid; n < NNODES; n += NT) atomicMax(&s_bc[7], s_tmp[n]);
    __syncthreads();
    const int maxd = s_bc[7];

    // ---- stable argsort by descending degree ----
    for (int d = maxd; d >= 0; --d) {
        int n0 = tid * 4;
        int f0 = (s_tmp[n0] == d), f1 = (s_tmp[n0 + 1] == d);
        int f2 = (s_tmp[n0 + 2] == d), f3 = (s_tmp[n0 + 3] == d);
        int tot;
        int off = blockScanExcl(f0 + f1 + f2 + f3, s_w, &tot);
        int idx = s_bc[4] + off;
        if (f0) s_order[idx++] = (unsigned short)n0;
        if (f1) s_order[idx++] = (unsigned short)(n0 + 1);
        if (f2) s_order[idx++] = (unsigned short)(n0 + 2);
        if (f3) s_order[idx++] = (unsigned short)(n0 + 3);
        __syncthreads();
        if (tid == 0) s_bc[4] += tot;
        __syncthreads();
    }

    // ---- iteration 0 (full-array scans, eager relabel) ----
    if (tid == 0) {
        int nd = s_order[0];
        s_bc[0] = nd; s_vis[nd] = 1;
    }
    __syncthreads();
    {
        const int node = s_bc[0];
        for (int e = tid; e < E0; e += NT) {
            int uu = U[e], vv = V[e];
            if (uu == node) {
                int w = vv; unsigned m = 1u << (w & 31);
                unsigned old = atomicOr(&s_hb[w >> 5], m);
                if (!(old & m)) { int i = atomicAdd(&s_bc[2], 1); s_tmp[i] = w; s_vis[w] = 1; }
            }
            if (vv == node) {
                int w = uu; unsigned m = 1u << (w & 31);
                unsigned old = atomicOr(&s_hb[w >> 5], m);
                if (!(old & m)) { int i = atomicAdd(&s_bc[2], 1); s_tmp[i] = w; s_vis[w] = 1; }
            }
        }
        __syncthreads();
        // eager relabel Hn = H \ {node} (U/V frozen afterwards)
        for (int e = tid; e < E0; e += NT) {
            int uu = U[e];
            if (uu != node && ((s_hb[uu >> 5] >> (uu & 31)) & 1)) U[e] = node;
            int vv = V[e];
            if (vv != node && ((s_hb[vv >> 5] >> (vv & 31)) & 1)) V[e] = node;
        }
        __syncthreads();
    }

    // ---- symmetry append (only iteration ever needing it), R4 windowed ----
    for (int i = tid; i < (1 << 19); i += NT) BM[i] = 0u;
    __syncthreads();
    for (int e = tid; e < E0; e += NT) {
        int uu = U[e], vv = V[e];
        if (uu != vv) {
            unsigned code = ((unsigned)uu << 12) | (unsigned)vv;
            atomicOr(&BM[code >> 5], 1u << (code & 31));
        }
    }
    __syncthreads();
    for (int t = 0; t < E0; t += NT) {
        int e = t + tid, flag = 0, uu = 0, vv = 0;
        if (e < E0) {
            uu = U[e]; vv = V[e];
            if (uu != vv) {
                unsigned rc = ((unsigned)vv << 12) | (unsigned)uu;
                unsigned old = atomicOr(&BM[rc >> 5], 0u);   // L2 read
                flag = !((old >> (rc & 31)) & 1u);
            }
        }
        int tot;
        int off = blockScanExcl(flag, s_w, &tot);
        if (flag) { int r = s_bc[5] + off; U[E0 + r] = vv; V[E0 + r] = uu; }
        __syncthreads();
        if (tid == 0) s_bc[5] += tot;
        __syncthreads();
    }
    const int E1 = E0 + s_bc[5];

    // ---- build static CSR (other-endpoint only; BM region reused as OTH/NBR) ----
    for (int n = tid; n < NNODES; n += NT) s_roff[n] = 0;
    __syncthreads();
    for (int e = tid; e < E1; e += NT) {
        int uu = U[e], vv = V[e];
        if (uu != vv) { atomicAdd(&s_roff[uu], 1); atomicAdd(&s_roff[vv], 1); }
    }
    __syncthreads();
    {
        int n0 = tid * 4;
        int c0 = s_roff[n0], c1 = s_roff[n0 + 1], c2 = s_roff[n0 + 2], c3 = s_roff[n0 + 3];
        int tot;
        int off = blockScanExcl(c0 + c1 + c2 + c3, s_w, &tot);
        int st = off;
        s_roff[n0] = st;     s_rend[n0] = st;     st += c0;
        s_roff[n0 + 1] = st; s_rend[n0 + 1] = st; st += c1;
        s_roff[n0 + 2] = st; s_rend[n0 + 2] = st; st += c2;
        s_roff[n0 + 3] = st; s_rend[n0 + 3] = st;
    }
    __syncthreads();
    for (int e = tid; e < E1; e += NT) {
        int uu = U[e], vv = V[e];
        if (uu != vv) {
            int p = atomicAdd(&s_rend[uu], 1);
            int q = atomicAdd(&s_rend[vv], 1);
            OTH[p] = vv; OTH[q] = uu;
        }
    }
    __syncthreads();
    {   // flush iter-0 staged H into global NBR
        const int cnt0 = s_bc[2];
        for (int i = tid; i < cnt0; i += NT) NBR[i] = s_tmp[i];
    }
    // ---- dump handoff state ----
    for (int i = tid; i < NNODES; i += NT) {
        int nd = (int)s_order[i];
        ORDV[i]  = nd | (s_vis[nd] ? 0x8000 : 0);
        ROFFG[i] = s_roff[i];
        RENDG[i] = s_rend[i];
    }
    if (tid == 0) { HAND[0] = E1; HAND[1] = s_bc[2]; HAND[2] = s_bc[0]; }
}

// ================= Phase A2: main loop, SINGLE WAVE, zero barriers =================
// R8 edits vs R6: register cursor (no s_nc atomics), lock-bit labels (no s_sel
// loads), explicit A/B half interleave (overlapped LDS chains).
__global__ __launch_bounds__(64, 1)
void phaseA2(const int* __restrict__ OTH, int* __restrict__ NBR,
             const int* __restrict__ ORDV, const int* __restrict__ ROFFG,
             const int* __restrict__ RENDG, const int* __restrict__ HAND,
             int* __restrict__ SEL, int* __restrict__ CNTS,
             int* __restrict__ NST, int* __restrict__ FIL, int* __restrict__ SC,
             int* __restrict__ LABG, int* __restrict__ RNKG)
{
    __shared__ unsigned short s_ordvis[NNODES];   // visbit(0x8000) | node id
    __shared__ unsigned short s_pos[NNODES];      // inverse permutation
    __shared__ unsigned short s_lab[NNODES];      // bit15 lock: is-hub / points-to-hub
    __shared__ unsigned short s_so[NNODES];       // selection order
    __shared__ int s_cnt[NNODES];                 // per-iteration |H_k|
    __shared__ int s_stamp[NNODES];               // dedup epoch; reused as rank
    __shared__ int s_roff[NNODES];
    __shared__ int s_rend[NNODES];

    const int ln = threadIdx.x;                   // single wave: tid == lane
    const unsigned long long ltm = (1ull << ln) - 1ull;
    const int cnt0 = HAND[1], hub0 = HAND[2];

    for (int i = ln; i < NNODES; i += 64) {
        int ov = ORDV[i];
        s_ordvis[i] = (unsigned short)ov;
        s_pos[ov & 0x7FFF] = (unsigned short)i;
        s_roff[i] = ROFFG[i];
        s_rend[i] = RENDG[i];
        s_lab[i] = (unsigned short)i;
        s_stamp[i] = 0; s_cnt[i] = 0;
    }
    int cursor = cnt0;                            // wave-uniform NBR cursor
    if (ln == 0) {
        s_lab[hub0] = (unsigned short)(0x8000 | hub0);
        s_so[0] = (unsigned short)hub0;
        s_cnt[0] = cnt0;
    }
    // single wave: in-order LDS pipeline gives visibility; no barriers.

    int p = 0, k = 1;
    for (;;) {
        // ---- selection: 64-wide window ballot over ordvis ----
        int node = -1;
        while (p < NNODES) {
            int idx = p + ln;
            int ov = (idx < NNODES) ? (int)s_ordvis[idx] : 0x8000;
            unsigned long long bal = __ballot(!(ov & 0x8000));
            if (bal != 0ull) {
                int sl = __ffsll((long long)bal) - 1;
                node = __shfl(ov, sl, 64) & 0x7FFF;
                p += sl + 1;
                break;
            }
            p += 64;
        }
        if (node < 0) break;
        if (ln == 0) {
            s_lab[node] = (unsigned short)(0x8000 | node);   // lock as hub
            s_so[k] = (unsigned short)node;
        }
        const int rb = s_roff[node], re = s_rend[node];
        const int begin = cursor;
        for (int s0 = rb; s0 < re; s0 += 128) {
            int sA = s0 + ln, sB = s0 + 64 + ln;
            int oA = (sA < re) ? OTH[sA] : -1;            // both L2 loads issue together
            int oB = (sB < re) ? OTH[sB] : -1;
            int rawA = (oA >= 0) ? (int)s_lab[oA] : -1;   // both LDS loads issue together
            int rawB = (oB >= 0) ? (int)s_lab[oB] : -1;
            int wA = rawA & 0x7FFF, wB = rawB & 0x7FFF;
            bool tA = (rawA >= 0) && (wA != node);
            bool tB = (rawB >= 0) && (wB != node);
            int oldA = tA ? atomicMax(&s_stamp[wA], k) : k;   // atomics overlap
            int oldB = tB ? atomicMax(&s_stamp[wB], k) : k;
            bool nA = tA && (oldA < k);
            bool nB = tB && (oldB < k);
            unsigned long long bA = __ballot(nA);
            unsigned long long bB = __ballot(nB);
            if (nA) {
                NBR[cursor + __popcll(bA & ltm)] = wA;
                s_ordvis[s_pos[wA]] = (unsigned short)(0x8000 | wA);
                if (!(rawA & 0x8000)) s_lab[wA] = (unsigned short)(0x8000 | node);
            }
            cursor += __popcll(bA);
            if (nB) {
                NBR[cursor + __popcll(bB & ltm)] = wB;
                s_ordvis[s_pos[wB]] = (unsigned short)(0x8000 | wB);
                if (!(rawB & 0x8000)) s_lab[wB] = (unsigned short)(0x8000 | node);
            }
            cursor += __popcll(bB);
        }
        if (ln == 0) s_cnt[k] = cursor - begin;
        k++;
    }
    const int K = k;

    // ---- rank of selected nodes (lab[n]==(n|lock)) among sorted(select) ----
    {
        int base = 0;
        for (int c = 0; c < NNODES / 64; ++c) {
            int n = c * 64 + ln;
            int f = ((int)s_lab[n] == (0x8000 | n));
            unsigned long long b = __ballot(f);
            s_stamp[n] = base + __popcll(b & ltm);
            base += __popcll(b);
        }
    }
    // ---- SEL / CNTS / NST (exclusive prefix of CNTS) ----
    {
        int nb = 0;
        for (int c = 0; c * 64 < K; ++c) {
            int i = c * 64 + ln;
            int cv = (i < K) ? s_cnt[i] : 0;
            int x = cv;
#pragma unroll
            for (int off = 1; off < 64; off <<= 1) {
                int t = __shfl_up(x, off, 64);
                if (ln >= off) x += t;
            }
            if (i < K) { NST[i] = nb + x - cv; CNTS[i] = cv; SEL[i] = (int)s_so[i]; }
            nb += __shfl(x, 63, 64);
        }
    }
    // ---- FIL forward-fill via ballot + clz ----
    {
        int carry = 0;
        for (int c = 0; c * 64 < K; ++c) {
            int i = c * 64 + ln;
            int f = (i < K) && (s_cnt[i] > 0);
            unsigned long long b = __ballot(f);
            unsigned long long m = b & ((ln == 63) ? ~0ull : ((1ull << (ln + 1)) - 1ull));
            int fil = m ? (c * 64 + 63 - __clzll(m)) : carry;
            if (i < K) FIL[i] = fil;
            carry = b ? (c * 64 + 63 - __clzll(b)) : carry;
        }
    }
    if (ln == 0) SC[0] = K;
    // ---- dump labels + ranks for A3 ----
    for (int i = ln; i < NNODES; i += 64) {
        LABG[i] = (int)s_lab[i] & 0x7FFF;
        RNKG[i] = s_stamp[i];
    }
}

// ================= Phase A3: final arc compaction + remap (NT=1024) =================
__global__ __launch_bounds__(NT, 1)
void phaseA3(const int* __restrict__ U, const int* __restrict__ V,
             const int* __restrict__ LABG, const int* __restrict__ RNKG,
             const int* __restrict__ HAND, int* __restrict__ SC,
             int* __restrict__ TMP, float* __restrict__ out)
{
    __shared__ unsigned short l_lab[NNODES];
    __shared__ int l_rnk[NNODES];
    __shared__ int s_w[16];
    __shared__ int s_base[1];

    const int tid = threadIdx.x;
    for (int i = tid; i < NNODES; i += NT) {
        l_lab[i] = (unsigned short)LABG[i];
        l_rnk[i] = RNKG[i];
    }
    if (tid == 0) s_base[0] = 0;
    __syncthreads();

    const int E1 = HAND[0];
    const int K  = SC[0];
    const size_t obase = (size_t)K * 8192;

    for (int t = 0; t < E1; t += NT) {
        int e = t + tid, flag = 0, ru = 0, rv = 0;
        if (e < E1) {
            int uu = (int)l_lab[U[e]], vv = (int)l_lab[V[e]];
            if (uu != vv) { flag = 1; ru = l_rnk[uu]; rv = l_rnk[vv]; }
        }
        int tot;
        int off = blockScanExcl(flag, s_w, &tot);
        if (flag) {
            int r = s_base[0] + off;
            out[obase + (size_t)r] = (float)ru;
            TMP[r] = rv;
        }
        __syncthreads();
        if (tid == 0) s_base[0] += tot;
        __syncthreads();
    }
    const int Ef = s_base[0];
    if (tid == 0) SC[1] = Ef;
    for (int r = tid; r < Ef; r += NT)
        out[obase + (size_t)Ef + (size_t)r] = (float)TMP[r];
}

// ---------------- Phase B: END rows (Dv | mean) with fill indirection ----------------
__global__ __launch_bounds__(256, 4)
void phaseB(const float* __restrict__ x,
            const float* __restrict__ W1, const float* __restrict__ W2,
            const float* __restrict__ B1, const float* __restrict__ B2,
            const int* __restrict__ NBR, const int* __restrict__ SEL,
            const int* __restrict__ CNTS, const int* __restrict__ NST,
            const int* __restrict__ FIL, const int* __restrict__ SC,
            float* __restrict__ out)
{
    const int K = SC[0];
    const int k = blockIdx.x;
    if (k >= K) return;
    const int kk   = FIL[k];
    const int node = SEL[kk];
    const int cnt  = CNTS[kk];
    const int st   = NST[kk];
    const int tid  = threadIdx.x;
    const float4* x4 = (const float4*)x;

    float4 acc[4];
#pragma unroll
    for (int j = 0; j < 4; j++) acc[j] = make_float4(0.f, 0.f, 0.f, 0.f);

    for (int r = 0; r < cnt; ++r) {
        const float4* row = x4 + (size_t)NBR[st + r] * 1024;
#pragma unroll
        for (int j = 0; j < 4; j++) {
            float4 t = row[tid + j * 256];
            acc[j].x += t.x; acc[j].y += t.y; acc[j].z += t.z; acc[j].w += t.w;
        }
    }

    const float fc  = (float)cnt;
    const float inv = 1.0f / (float)(cnt > 1 ? cnt : 1);
    const float4* xr = x4 + (size_t)node * 1024;
    float4* o4 = (float4*)(out + (size_t)k * 8192);

#pragma unroll
    for (int j = 0; j < 4; j++) {
        int c = tid + j * 256;
        float4 w1 = ((const float4*)W1)[c], b1 = ((const float4*)B1)[c];
        float4 w2 = ((const float4*)W2)[c], b2 = ((const float4*)B2)[c];
        float4 xv = xr[c];
        float4 pd, pm;
        pd.x = xv.x * w2.x + b2.x;
        pd.y = xv.y * w2.y + b2.y;
        pd.z = xv.z * w2.z + b2.z;
        pd.w = xv.w * w2.w + b2.w;
        pm.x = (acc[j].x * w1.x + fc * b1.x) * inv;
        pm.y = (acc[j].y * w1.y + fc * b1.y) * inv;
        pm.z = (acc[j].z * w1.z + fc * b1.z) * inv;
        pm.w = (acc[j].w * w1.w + fc * b1.w) * inv;
        o4[c] = pd;
        o4[1024 + c] = pm;
    }
}

extern "C" void kernel_launch(void* const* d_in, const int* in_sizes, int n_in,
                              void* d_out, int out_size, void* d_ws, size_t ws_size,
                              hipStream_t stream)
{
    const float* x  = (const float*)d_in[0];
    const int*   ei = (const int*)d_in[1];
    const float* W1 = (const float*)d_in[2];
    const float* W2 = (const float*)d_in[3];
    const float* B1 = (const float*)d_in[4];
    const float* B2 = (const float*)d_in[5];
    const int E0 = in_sizes[1] / 2;

    char* w = (char*)d_ws;
    int* U = (int*)w;                         // [ECAP]
    int* V = U + ECAP;                        // [ECAP]
    unsigned int* BM = (unsigned int*)(V + ECAP);   // 2 MB bitmap (iter-0 only)
    int* OTH = (int*)BM;                      // [2*ECAP] static CSR other-endpoint
    int* NBR = OTH + 2 * ECAP;                // [2*ECAP]
    int* TMP = NBR + 2 * ECAP;                // [2*ECAP] A3 scratch
    char* meta = (char*)BM + (2u << 20);
    int* SEL   = (int*)meta;
    int* CNTS  = SEL  + NNODES;
    int* NST   = CNTS + NNODES;
    int* FIL   = NST  + NNODES;
    int* SC    = FIL  + NNODES;               // [16]
    int* ORDV  = SC   + 16;
    int* ROFFG = ORDV + NNODES;
    int* RENDG = ROFFG + NNODES;
    int* LABG  = RENDG + NNODES;
    int* RNKG  = LABG + NNODES;
    int* HAND  = RNKG + NNODES;               // [16]
    float* out = (float*)d_out;

    hipLaunchKernelGGL(phaseA1, dim3(1), dim3(NT), 0, stream,
                       ei, E0, U, V, BM, NBR, OTH, ORDV, ROFFG, RENDG, HAND);
    hipLaunchKernelGGL(phaseA2, dim3(1), dim3(64), 0, stream,
                       OTH, NBR, ORDV, ROFFG, RENDG, HAND,
                       SEL, CNTS, NST, FIL, SC, LABG, RNKG);
    hipLaunchKernelGGL(phaseA3, dim3(1), dim3(NT), 0, stream,
                       U, V, LABG, RNKG, HAND, SC, TMP, out);
    hipLaunchKernelGGL(phaseB, dim3(NNODES), dim3(256), 0, stream,
                       x, W1, W2, B1, B2, NBR, SEL, CNTS, NST, FIL, SC, out);
}